// Round 11
// baseline (1542.549 us; speedup 1.0000x reference)
//
#include <hip/hip_runtime.h>
#include <cstdint>
#include <cstddef>

constexpr int LSEQ = 1000;   // sequence length
constexpr int NB   = 128;    // batch
constexpr int CINP = 12;     // input channels
constexpr int HID  = 128;    // lstm hidden
constexpr int NGATE = 4 * HID;  // 512
constexpr int DMOD = 128;    // d_model
constexpr int DINN = 256;    // d_inner
constexpr int NCL  = 5;

typedef unsigned short ushort_t;
typedef _Float16 half2_t __attribute__((ext_vector_type(2)));

__device__ __forceinline__ float bf2f(ushort_t u) {
  uint32_t b = ((uint32_t)u) << 16;
  float f; __builtin_memcpy(&f, &b, 4); return f;
}
__device__ __forceinline__ ushort_t f2bf(float f) {
  uint32_t b; __builtin_memcpy(&b, &f, 4);
  uint32_t r = (b + 0x7fffu + ((b >> 16) & 1u)) >> 16;
  return (ushort_t)r;
}
__device__ __forceinline__ half2_t u2h2(uint32_t v) {
  half2_t h; __builtin_memcpy(&h, &v, 4); return h;
}
__device__ __forceinline__ uint32_t h22u(half2_t h) {
  uint32_t v; __builtin_memcpy(&v, &h, 4); return v;
}
// two bf16 packed in u32 -> two f16 packed in u32
__device__ __forceinline__ uint32_t bfpair_to_h2(uint32_t v) {
  half2_t h;
  h.x = (_Float16)bf2f((ushort_t)(v & 0xffff));
  h.y = (_Float16)bf2f((ushort_t)(v >> 16));
  return h22u(h);
}

#if __has_builtin(__builtin_amdgcn_fdot2)
__device__ __forceinline__ float FDOT2(half2_t a, half2_t b, float c) {
  return __builtin_amdgcn_fdot2(a, b, c, false);
}
#else
__device__ __forceinline__ float FDOT2(half2_t a, half2_t b, float c) {
  return c + (float)a.x * (float)b.x + (float)a.y * (float)b.y;
}
#endif

// LDS-only barrier: drains lgkmcnt but NOT vmcnt (global stores keep flowing).
__device__ __forceinline__ void bar_lgkm() {
  asm volatile("s_waitcnt lgkmcnt(0)\n\ts_barrier" ::: "memory");
}

// ---------------------------------------------------------------------------
// K0: fold input_proj into in_proj; emit Weff PRE-PACKED as f16 pairs.
__global__ __launch_bounds__(256) void k0_weff(
    const float* __restrict__ ipw, const float* __restrict__ Wp,
    const float* __restrict__ bp, uint32_t* __restrict__ Weffh,
    float* __restrict__ beff) {
  int idx = blockIdx.x * 256 + threadIdx.x;   // grid 128 blocks -> 32768
  if (idx < NGATE * 64) {
    int e = idx >> 6, j = idx & 63;
    float a0 = 0.f, a1 = 0.f;
    for (int d = 0; d < DMOD; ++d) {
      float w = ipw[e * DMOD + d];
      a0 += w * Wp[d * HID + 2 * j];
      a1 += w * Wp[d * HID + 2 * j + 1];
    }
    half2_t h; h.x = (_Float16)a0; h.y = (_Float16)a1;
    Weffh[idx] = h22u(h);
  }
  if (idx < NGATE) {
    float acc = 0.f;
    for (int d = 0; d < DMOD; ++d) acc += ipw[idx * DMOD + d] * bp[d];
    beff[idx] = acc;
  }
}

// ---------------------------------------------------------------------------
// K1: LSTM. One block per batch; 256 threads; thread t owns gate rows t AND
//     t+256 (h fragments read ONCE, used for both rows -> halves the LDS
//     broadcast traffic that dominates this kernel). Same lgkm-only barrier
//     structure and t<128 nonlinearity as the proven 753us R6 kernel.
__global__ __launch_bounds__(256) void k1_lstm(
    const float* __restrict__ x, const float* __restrict__ W_ih,
    const float* __restrict__ W_hh, const float* __restrict__ b_ih,
    const float* __restrict__ b_hh, ushort_t* __restrict__ hout) {
  __shared__ __align__(16) float x_sh[LSEQ * CINP];      // 48 KB
  __shared__ __align__(16) ushort_t h_sh[HID];           // f16 bits
  __shared__ float g_sh[NGATE];
  const int t = threadIdx.x;          // 0..255
  const int b = blockIdx.x;
  const int rA = t;                   // gate row A
  const int rB = t + 256;             // gate row B

  const float4* xg4 = reinterpret_cast<const float4*>(x + (size_t)b * LSEQ * CINP);
  float4* xs4 = reinterpret_cast<float4*>(x_sh);
  for (int i = t; i < LSEQ * CINP / 4; i += 256) xs4[i] = xg4[i];

  // W_hh rows rA, rB -> 64 packed f16 pairs each
  half2_t wa2[64], wb2[64];
  {
    const float4* wa4 = reinterpret_cast<const float4*>(W_hh) + rA * (HID / 4);
    const float4* wb4 = reinterpret_cast<const float4*>(W_hh) + rB * (HID / 4);
#pragma unroll
    for (int k = 0; k < HID / 4; ++k) {
      float4 v = wa4[k];
      half2_t a; a.x = (_Float16)v.x; a.y = (_Float16)v.y;
      half2_t c; c.x = (_Float16)v.z; c.y = (_Float16)v.w;
      wa2[2 * k] = a; wa2[2 * k + 1] = c;
      float4 u = wb4[k];
      half2_t d; d.x = (_Float16)u.x; d.y = (_Float16)u.y;
      half2_t e; e.x = (_Float16)u.z; e.y = (_Float16)u.w;
      wb2[2 * k] = d; wb2[2 * k + 1] = e;
    }
  }
  float wia[CINP], wib[CINP];
#pragma unroll
  for (int c = 0; c < CINP; ++c) {
    wia[c] = W_ih[rA * CINP + c];
    wib[c] = W_ih[rB * CINP + c];
  }
  const float biasA = b_ih[rA] + b_hh[rA];
  const float biasB = b_ih[rB] + b_hh[rB];

  float cstate = 0.f;
  if (t < HID) h_sh[t] = 0;
  __syncthreads();   // full barrier once (covers global->LDS staging)

  for (int l = 0; l < LSEQ; ++l) {
    const float* xr = &x_sh[l * CINP];
    float pa0 = biasA, pa1 = 0.f, pa2 = 0.f, pa3 = 0.f;
    float pb0 = biasB, pb1 = 0.f, pb2 = 0.f, pb3 = 0.f;
#pragma unroll
    for (int c = 0; c < CINP; c += 4) {
      float x0 = xr[c], x1 = xr[c + 1], x2 = xr[c + 2], x3 = xr[c + 3];
      pa0 += x0 * wia[c];     pa1 += x1 * wia[c + 1];
      pa2 += x2 * wia[c + 2]; pa3 += x3 * wia[c + 3];
      pb0 += x0 * wib[c];     pb1 += x1 * wib[c + 1];
      pb2 += x2 * wib[c + 2]; pb3 += x3 * wib[c + 3];
    }
    const uint4* h4 = reinterpret_cast<const uint4*>(h_sh);
#pragma unroll
    for (int kk = 0; kk < 16; ++kk) {
      uint4 hv = h4[kk];   // read ONCE, feeds both rows
      half2_t h0 = u2h2(hv.x), h1 = u2h2(hv.y), h2 = u2h2(hv.z), h3 = u2h2(hv.w);
      pa0 = FDOT2(h0, wa2[4 * kk],     pa0);
      pa1 = FDOT2(h1, wa2[4 * kk + 1], pa1);
      pa2 = FDOT2(h2, wa2[4 * kk + 2], pa2);
      pa3 = FDOT2(h3, wa2[4 * kk + 3], pa3);
      pb0 = FDOT2(h0, wb2[4 * kk],     pb0);
      pb1 = FDOT2(h1, wb2[4 * kk + 1], pb1);
      pb2 = FDOT2(h2, wb2[4 * kk + 2], pb2);
      pb3 = FDOT2(h3, wb2[4 * kk + 3], pb3);
    }
    g_sh[rA] = (pa0 + pa1) + (pa2 + pa3);
    g_sh[rB] = (pb0 + pb1) + (pb2 + pb3);
    bar_lgkm();
    if (t < HID) {   // threads 0..127 = 2 waves (wave-uniform branch)
      float gi = g_sh[t], gf = g_sh[t + 128], gg = g_sh[t + 256], go = g_sh[t + 384];
      float si = 1.f / (1.f + __expf(-gi));
      float sf = 1.f / (1.f + __expf(-gf));
      float so = 1.f / (1.f + __expf(-go));
      float tg = 1.f - 2.f / (__expf(2.f * gg) + 1.f);
      cstate = sf * cstate + si * tg;
      float th = 1.f - 2.f / (__expf(2.f * cstate) + 1.f);
      float hv = so * th;
      _Float16 hh = (_Float16)hv;
      ushort_t hb; __builtin_memcpy(&hb, &hh, 2);
      h_sh[t] = hb;
      hout[((size_t)b * LSEQ + l) * HID + t] = f2bf(hv);  // vmcnt never drained in-loop
    }
    bar_lgkm();
  }
}

// ---------------------------------------------------------------------------
// K2: xz = h @ Weff.T + beff via packed-f16 dot2. 64x64 tile, LDS 34 KB,
//     b64 LDS reads (stride 66 words). cols<256 -> xi; >=256 -> silu -> sz.
__global__ __launch_bounds__(256) void k2_xz(
    const ushort_t* __restrict__ hbuf, const uint32_t* __restrict__ Weffh,
    const float* __restrict__ beff, ushort_t* __restrict__ xi,
    ushort_t* __restrict__ sz) {
  constexpr int S = 66;                 // u32 stride per 64-pair row
  __shared__ __align__(16) uint32_t As[64 * S];
  __shared__ __align__(16) uint32_t Bs[64 * S];
  const int tid = threadIdx.x;
  const size_t m0 = (size_t)blockIdx.x * 64;
  const int n0 = blockIdx.y * 64;

  const uint4* h4g = reinterpret_cast<const uint4*>(hbuf);
  for (int i = tid; i < 64 * 16; i += 256) {
    int row = i >> 4, c = i & 15;
    uint4 v = h4g[(m0 + row) * 16 + c];
    uint32_t* p = &As[row * S + c * 4];
    p[0] = bfpair_to_h2(v.x); p[1] = bfpair_to_h2(v.y);
    p[2] = bfpair_to_h2(v.z); p[3] = bfpair_to_h2(v.w);
  }
  const uint4* w4g = reinterpret_cast<const uint4*>(Weffh);
  for (int i = tid; i < 64 * 16; i += 256) {
    int row = i >> 4, c = i & 15;
    uint4 v = w4g[(size_t)(n0 + row) * 16 + c];
    uint32_t* p = &Bs[row * S + c * 4];
    p[0] = v.x; p[1] = v.y; p[2] = v.z; p[3] = v.w;
  }
  __syncthreads();

  const int tx = tid & 15, ty = tid >> 4;
  float acc[4][4] = {};
  const uint32_t* ap = &As[(ty * 4) * S];
  const uint32_t* bp = &Bs[(tx * 4) * S];
#pragma unroll 4
  for (int kk = 0; kk < 32; ++kk) {      // 2 k-pairs (4 k) per iter
    uint2 a0 = *reinterpret_cast<const uint2*>(&ap[kk * 2]);
    uint2 a1 = *reinterpret_cast<const uint2*>(&ap[S + kk * 2]);
    uint2 a2 = *reinterpret_cast<const uint2*>(&ap[2 * S + kk * 2]);
    uint2 a3 = *reinterpret_cast<const uint2*>(&ap[3 * S + kk * 2]);
    uint2 b0 = *reinterpret_cast<const uint2*>(&bp[kk * 2]);
    uint2 b1 = *reinterpret_cast<const uint2*>(&bp[S + kk * 2]);
    uint2 b2 = *reinterpret_cast<const uint2*>(&bp[2 * S + kk * 2]);
    uint2 b3 = *reinterpret_cast<const uint2*>(&bp[3 * S + kk * 2]);
    acc[0][0] = FDOT2(u2h2(a0.x), u2h2(b0.x), acc[0][0]);
    acc[0][1] = FDOT2(u2h2(a0.x), u2h2(b1.x), acc[0][1]);
    acc[0][2] = FDOT2(u2h2(a0.x), u2h2(b2.x), acc[0][2]);
    acc[0][3] = FDOT2(u2h2(a0.x), u2h2(b3.x), acc[0][3]);
    acc[1][0] = FDOT2(u2h2(a1.x), u2h2(b0.x), acc[1][0]);
    acc[1][1] = FDOT2(u2h2(a1.x), u2h2(b1.x), acc[1][1]);
    acc[1][2] = FDOT2(u2h2(a1.x), u2h2(b2.x), acc[1][2]);
    acc[1][3] = FDOT2(u2h2(a1.x), u2h2(b3.x), acc[1][3]);
    acc[2][0] = FDOT2(u2h2(a2.x), u2h2(b0.x), acc[2][0]);
    acc[2][1] = FDOT2(u2h2(a2.x), u2h2(b1.x), acc[2][1]);
    acc[2][2] = FDOT2(u2h2(a2.x), u2h2(b2.x), acc[2][2]);
    acc[2][3] = FDOT2(u2h2(a2.x), u2h2(b3.x), acc[2][3]);
    acc[3][0] = FDOT2(u2h2(a3.x), u2h2(b0.x), acc[3][0]);
    acc[3][1] = FDOT2(u2h2(a3.x), u2h2(b1.x), acc[3][1]);
    acc[3][2] = FDOT2(u2h2(a3.x), u2h2(b2.x), acc[3][2]);
    acc[3][3] = FDOT2(u2h2(a3.x), u2h2(b3.x), acc[3][3]);
    acc[0][0] = FDOT2(u2h2(a0.y), u2h2(b0.y), acc[0][0]);
    acc[0][1] = FDOT2(u2h2(a0.y), u2h2(b1.y), acc[0][1]);
    acc[0][2] = FDOT2(u2h2(a0.y), u2h2(b2.y), acc[0][2]);
    acc[0][3] = FDOT2(u2h2(a0.y), u2h2(b3.y), acc[0][3]);
    acc[1][0] = FDOT2(u2h2(a1.y), u2h2(b0.y), acc[1][0]);
    acc[1][1] = FDOT2(u2h2(a1.y), u2h2(b1.y), acc[1][1]);
    acc[1][2] = FDOT2(u2h2(a1.y), u2h2(b2.y), acc[1][2]);
    acc[1][3] = FDOT2(u2h2(a1.y), u2h2(b3.y), acc[1][3]);
    acc[2][0] = FDOT2(u2h2(a2.y), u2h2(b0.y), acc[2][0]);
    acc[2][1] = FDOT2(u2h2(a2.y), u2h2(b1.y), acc[2][1]);
    acc[2][2] = FDOT2(u2h2(a2.y), u2h2(b2.y), acc[2][2]);
    acc[2][3] = FDOT2(u2h2(a2.y), u2h2(b3.y), acc[2][3]);
    acc[3][0] = FDOT2(u2h2(a3.y), u2h2(b0.y), acc[3][0]);
    acc[3][1] = FDOT2(u2h2(a3.y), u2h2(b1.y), acc[3][1]);
    acc[3][2] = FDOT2(u2h2(a3.y), u2h2(b2.y), acc[3][2]);
    acc[3][3] = FDOT2(u2h2(a3.y), u2h2(b3.y), acc[3][3]);
  }

  const int col = n0 + tx * 4;
  float4 be = *reinterpret_cast<const float4*>(&beff[col]);
#pragma unroll
  for (int i = 0; i < 4; ++i) {
    size_t row = m0 + ty * 4 + i;
    float v0 = acc[i][0] + be.x, v1 = acc[i][1] + be.y;
    float v2 = acc[i][2] + be.z, v3 = acc[i][3] + be.w;
    ushort4 o;
    if (n0 < 256) {
      o.x = f2bf(v0); o.y = f2bf(v1); o.z = f2bf(v2); o.w = f2bf(v3);
      *reinterpret_cast<ushort4*>(&xi[row * 256 + col]) = o;
    } else {
      o.x = f2bf(v0 / (1.f + __expf(-v0)));
      o.y = f2bf(v1 / (1.f + __expf(-v1)));
      o.z = f2bf(v2 / (1.f + __expf(-v2)));
      o.w = f2bf(v3 / (1.f + __expf(-v3)));
      *reinterpret_cast<ushort4*>(&sz[row * 256 + (col - 256)]) = o;
    }
  }
}

// ---------------------------------------------------------------------------
// K3: causal depthwise conv (DC=4) + silu. 4 timesteps per block, register
//     halo. Blocks never straddle a batch boundary (1000 % 4 == 0).
__global__ __launch_bounds__(256) void k3_conv(
    const ushort_t* __restrict__ xi, const float* __restrict__ cw,
    const float* __restrict__ cb, ushort_t* __restrict__ xs) {
  const int d = threadIdx.x;
  const size_t bl0 = (size_t)blockIdx.x * 4;
  const int l0 = (int)(bl0 % LSEQ);
  float w0 = cw[d * 4], w1 = cw[d * 4 + 1], w2 = cw[d * 4 + 2], w3 = cw[d * 4 + 3];
  const float cbv = cb[d];
  const ushort_t* p = &xi[bl0 * 256 + d];
  float xm3 = (l0 >= 3) ? bf2f(p[-768]) : 0.f;
  float xm2 = (l0 >= 2) ? bf2f(p[-512]) : 0.f;
  float xm1 = (l0 >= 1) ? bf2f(p[-256]) : 0.f;
  float x0 = bf2f(p[0]);
  float x1 = bf2f(p[256]);
  float x2 = bf2f(p[512]);
  float x3 = bf2f(p[768]);
  float o0 = cbv + w0 * xm3 + w1 * xm2 + w2 * xm1 + w3 * x0;
  float o1 = cbv + w0 * xm2 + w1 * xm1 + w2 * x0 + w3 * x1;
  float o2 = cbv + w0 * xm1 + w1 * x0 + w2 * x1 + w3 * x2;
  float o3 = cbv + w0 * x0 + w1 * x1 + w2 * x2 + w3 * x3;
  ushort_t* q = &xs[bl0 * 256 + d];
  q[0]   = f2bf(o0 / (1.f + __expf(-o0)));
  q[256] = f2bf(o1 / (1.f + __expf(-o1)));
  q[512] = f2bf(o2 / (1.f + __expf(-o2)));
  q[768] = f2bf(o3 / (1.f + __expf(-o3)));
}

// ---------------------------------------------------------------------------
// K4: x_dbl = xs @ x_proj_w.T (N=40) via packed f16 dot2.
//     b64 LDS reads: stride 134 (even -> 8B aligned rows); 11 reads per 2 K.
__global__ __launch_bounds__(256) void k4_xdbl(
    const ushort_t* __restrict__ xs, const float* __restrict__ xpw,
    float* __restrict__ dtg, float* __restrict__ bc) {
  constexpr int XSTR = 134;
  __shared__ __align__(16) uint32_t xsh[64 * XSTR];
  __shared__ __align__(16) uint32_t wsh[40 * 128];
  const int tid = threadIdx.x;
  const size_t r0 = (size_t)blockIdx.x * 64;

  for (int i = tid; i < 64 * 128; i += 256) {
    int row = i >> 7, kk = i & 127;
    uint32_t v = *reinterpret_cast<const uint32_t*>(&xs[(r0 + row) * 256 + kk * 2]);
    xsh[row * XSTR + kk] = bfpair_to_h2(v);
  }
  for (int i = tid; i < 40 * 128; i += 256) {
    int c = i >> 7, kk = i & 127;
    half2_t h;
    h.x = (_Float16)xpw[c * 256 + kk * 2];
    h.y = (_Float16)xpw[c * 256 + kk * 2 + 1];
    wsh[i] = h22u(h);
  }
  __syncthreads();

  const int row = tid & 63;
  const int cg = tid >> 6;   // wave-uniform
  float acc[10] = {};
  for (int kk2 = 0; kk2 < 64; ++kk2) {
    uint2 xv = *reinterpret_cast<const uint2*>(&xsh[row * XSTR + kk2 * 2]);
    half2_t x0 = u2h2(xv.x), x1 = u2h2(xv.y);
#pragma unroll
    for (int i = 0; i < 10; ++i) {
      uint2 wv = *reinterpret_cast<const uint2*>(&wsh[(cg + 4 * i) * 128 + kk2 * 2]);
      acc[i] = FDOT2(x0, u2h2(wv.x), acc[i]);
      acc[i] = FDOT2(x1, u2h2(wv.y), acc[i]);
    }
  }
#pragma unroll
  for (int i = 0; i < 10; ++i) {
    int c = cg + 4 * i;
    if (c < 8) dtg[(r0 + row) * 8 + c] = acc[i];
    else bc[(r0 + row) * 32 + (c - 8)] = acc[i];
  }
}

// ---------------------------------------------------------------------------
// K5: selective scan. 8 threads per (b,d), 2 states each. NO in-loop shfl:
//     z is group-uniform, so each thread accumulates y_part*z privately and
//     the 8-lane reduction happens ONCE after the loop. D-term via accD.
__global__ __launch_bounds__(256) void k5_scan(
    const float* __restrict__ dtg, const ushort_t* __restrict__ xs,
    const ushort_t* __restrict__ sz, const float* __restrict__ bc,
    const float* __restrict__ A_log, const float* __restrict__ Dv,
    const float* __restrict__ dtw, const float* __restrict__ dtb,
    float* __restrict__ ysum) {
  const int b  = blockIdx.x >> 3;
  const int d  = ((blockIdx.x & 7) << 5) + (threadIdx.x >> 3);  // 0..255
  const int sg = threadIdx.x & 7;                                // 2 states each

  const float Aa0 = -__expf(A_log[d * 16 + sg * 2]);
  const float Aa1 = -__expf(A_log[d * 16 + sg * 2 + 1]);
  float w8[8];
#pragma unroll
  for (int r = 0; r < 8; ++r) w8[r] = dtw[d * 8 + r];
  const float db = dtb[d];
  const float DD = Dv[d];

  float h0 = 0.f, h1 = 0.f;
  float acc = 0.f, accD = 0.f;
  const size_t base = (size_t)b * LSEQ;

  float4 dta_c = *reinterpret_cast<const float4*>(&dtg[base * 8]);
  float4 dtb_c = *reinterpret_cast<const float4*>(&dtg[base * 8 + 4]);
  float  xv_c  = bf2f(xs[base * 256 + d]);
  float  zv_c  = bf2f(sz[base * 256 + d]);
  float2 bv_c  = *reinterpret_cast<const float2*>(&bc[base * 32 + sg * 2]);
  float2 cv_c  = *reinterpret_cast<const float2*>(&bc[base * 32 + 16 + sg * 2]);

  for (int l = 0; l < LSEQ; ++l) {
    const size_t nrow = base + ((l + 1 < LSEQ) ? (l + 1) : l);
    float4 dta_n = *reinterpret_cast<const float4*>(&dtg[nrow * 8]);
    float4 dtb_n = *reinterpret_cast<const float4*>(&dtg[nrow * 8 + 4]);
    float  xv_n  = bf2f(xs[nrow * 256 + d]);
    float  zv_n  = bf2f(sz[nrow * 256 + d]);
    float2 bv_n  = *reinterpret_cast<const float2*>(&bc[nrow * 32 + sg * 2]);
    float2 cv_n  = *reinterpret_cast<const float2*>(&bc[nrow * 32 + 16 + sg * 2]);

    float a = db + dta_c.x * w8[0] + dta_c.y * w8[1] + dta_c.z * w8[2] + dta_c.w * w8[3]
                 + dtb_c.x * w8[4] + dtb_c.y * w8[5] + dtb_c.z * w8[6] + dtb_c.w * w8[7];
    float dl = (a > 20.f) ? a : __logf(1.f + __expf(a));
    float dx = dl * xv_c;
    h0 = __expf(dl * Aa0) * h0 + dx * bv_c.x;
    h1 = __expf(dl * Aa1) * h1 + dx * bv_c.y;
    acc += (h0 * cv_c.x + h1 * cv_c.y) * zv_c;   // partial y * z (z group-uniform)
    accD += xv_c * zv_c;                          // D-term, folded once at end

    dta_c = dta_n; dtb_c = dtb_n;
    xv_c = xv_n; zv_c = zv_n; bv_c = bv_n; cv_c = cv_n;
  }
  if (sg == 0) acc += DD * accD;
  acc += __shfl_xor(acc, 1);
  acc += __shfl_xor(acc, 2);
  acc += __shfl_xor(acc, 4);
  if (sg == 0) ysum[b * 256 + d] = acc;
}

// ---------------------------------------------------------------------------
// K6: head. pooled = ysum@opw.T/L ; fc1+relu ; fc2.
__global__ __launch_bounds__(128) void k6_head(
    const float* __restrict__ ysum, const float* __restrict__ opw,
    const float* __restrict__ fc1w, const float* __restrict__ fc1b,
    const float* __restrict__ fc2w, const float* __restrict__ fc2b,
    float* __restrict__ out) {
  __shared__ float ys[256], pool[128], fcs[128];
  const int b = blockIdx.x, t = threadIdx.x;
  for (int i = t; i < 256; i += 128) ys[i] = ysum[b * 256 + i];
  __syncthreads();
  float a = 0.f;
  for (int e = 0; e < 256; ++e) a += opw[t * 256 + e] * ys[e];
  pool[t] = a * (1.0f / (float)LSEQ);
  __syncthreads();
  float a1 = fc1b[t];
  for (int d2 = 0; d2 < 128; ++d2) a1 += fc1w[t * 128 + d2] * pool[d2];
  fcs[t] = fmaxf(a1, 0.f);
  __syncthreads();
  if (t < NCL) {
    float o = fc2b[t];
    for (int f = 0; f < 128; ++f) o += fc2w[t * 128 + f] * fcs[f];
    out[b * NCL + t] = o;
  }
}

// ---------------------------------------------------------------------------
extern "C" void kernel_launch(void* const* d_in, const int* in_sizes, int n_in,
                              void* d_out, int out_size, void* d_ws, size_t ws_size,
                              hipStream_t stream) {
  const float* x     = (const float*)d_in[0];
  const float* W_ih  = (const float*)d_in[1];
  const float* W_hh  = (const float*)d_in[2];
  const float* b_ih  = (const float*)d_in[3];
  const float* b_hh  = (const float*)d_in[4];
  const float* Wp    = (const float*)d_in[5];
  const float* bp    = (const float*)d_in[6];
  const float* ipw   = (const float*)d_in[7];
  const float* cw    = (const float*)d_in[8];
  const float* cb    = (const float*)d_in[9];
  const float* xpw   = (const float*)d_in[10];
  const float* dtw   = (const float*)d_in[11];
  const float* dtb   = (const float*)d_in[12];
  const float* A_log = (const float*)d_in[13];
  const float* Dv    = (const float*)d_in[14];
  const float* opw   = (const float*)d_in[15];
  const float* fc1w  = (const float*)d_in[16];
  const float* fc1b  = (const float*)d_in[17];
  const float* fc2w  = (const float*)d_in[18];
  const float* fc2b  = (const float*)d_in[19];
  float* out = (float*)d_out;

  const size_t A_WEFF = 131072;                          // packed f16 pairs
  const size_t A_BEFF = 4096, A_YSUM = 131072;
  const size_t A_HBUF = (size_t)NB * LSEQ * HID * 2;     // 32.77 MB
  const size_t A_XS   = (size_t)NB * LSEQ * DINN * 2;    // 65.54 MB
  const size_t A_SZ   = A_XS;                            // 65.54 MB
  const size_t A_DT   = (size_t)NB * LSEQ * 8 * 4;       // 4.10 MB
  const size_t A_BC   = (size_t)NB * LSEQ * 32 * 4;      // 16.38 MB
  const size_t FIXED_WIDE = A_WEFF + A_BEFF + A_YSUM + A_HBUF + A_XS + A_SZ + A_DT + A_BC;

  int nb_w = 0;
  for (int c = 128; c >= 8; c >>= 1) {
    if (FIXED_WIDE + (size_t)c * LSEQ * DINN * 2 <= ws_size) { nb_w = c; break; }
  }

  if (nb_w > 0) {
    char* p = (char*)d_ws;
    uint32_t* Weffh = (uint32_t*)p; p += A_WEFF;
    float*    beff = (float*)p;    p += A_BEFF;
    float*    ysum = (float*)p;    p += A_YSUM;
    ushort_t* hbuf = (ushort_t*)p; p += A_HBUF;
    ushort_t* xsb  = (ushort_t*)p; p += A_XS;
    ushort_t* szb  = (ushort_t*)p; p += A_SZ;
    float*    dtg  = (float*)p;    p += A_DT;
    float*    bcb  = (float*)p;    p += A_BC;
    ushort_t* xib  = (ushort_t*)p;

    hipLaunchKernelGGL(k0_weff, dim3(128), dim3(256), 0, stream, ipw, Wp, bp, Weffh, beff);
    hipLaunchKernelGGL(k1_lstm, dim3(NB), dim3(256), 0, stream, x, W_ih, W_hh, b_ih, b_hh, hbuf);

    for (int b0 = 0; b0 < NB; b0 += nb_w) {
      const int rows = nb_w * LSEQ;
      const size_t ro = (size_t)b0 * LSEQ;
      hipLaunchKernelGGL(k2_xz, dim3(rows / 64, 8), dim3(256), 0, stream,
                         hbuf + ro * HID, Weffh, beff, xib, szb + ro * DINN);
      hipLaunchKernelGGL(k3_conv, dim3(rows / 4), dim3(256), 0, stream,
                         xib, cw, cb, xsb + ro * DINN);
      hipLaunchKernelGGL(k4_xdbl, dim3(rows / 64), dim3(256), 0, stream,
                         xsb + ro * DINN, xpw, dtg + ro * 8, bcb + ro * 32);
    }
    hipLaunchKernelGGL(k5_scan, dim3(NB * 8), dim3(256), 0, stream,
                       dtg, xsb, szb, bcb, A_log, Dv, dtw, dtb, ysum);
    hipLaunchKernelGGL(k6_head, dim3(NB), dim3(128), 0, stream,
                       ysum, opw, fc1w, fc1b, fc2w, fc2b, out);
    return;
  }

  // --- fallback: fully chunked ---
  const size_t FIXED = A_WEFF + A_BEFF + A_YSUM + A_HBUF;
  const size_t PERB = (size_t)LSEQ * DINN * 2 * 3 + (size_t)LSEQ * 8 * 4 + (size_t)LSEQ * 32 * 4;
  int nb = 8;
  for (int c = 128; c >= 8; c >>= 1) {
    if (FIXED + (size_t)c * PERB <= ws_size) { nb = c; break; }
  }
  char* p = (char*)d_ws;
  uint32_t* Weffh = (uint32_t*)p; p += A_WEFF;
  float*    beff = (float*)p;    p += A_BEFF;
  float*    ysum = (float*)p;    p += A_YSUM;
  ushort_t* hbuf = (ushort_t*)p; p += A_HBUF;
  ushort_t* xib  = (ushort_t*)p; p += (size_t)nb * LSEQ * DINN * 2;
  ushort_t* szb  = (ushort_t*)p; p += (size_t)nb * LSEQ * DINN * 2;
  ushort_t* xsb  = (ushort_t*)p; p += (size_t)nb * LSEQ * DINN * 2;
  float*    dtg  = (float*)p;    p += (size_t)nb * LSEQ * 8 * 4;
  float*    bcb  = (float*)p;

  hipLaunchKernelGGL(k0_weff, dim3(128), dim3(256), 0, stream, ipw, Wp, bp, Weffh, beff);
  hipLaunchKernelGGL(k1_lstm, dim3(NB), dim3(256), 0, stream, x, W_ih, W_hh, b_ih, b_hh, hbuf);
  for (int b0 = 0; b0 < NB; b0 += nb) {
    const int rows = nb * LSEQ;
    hipLaunchKernelGGL(k2_xz, dim3(rows / 64, 8), dim3(256), 0, stream,
                       hbuf + (size_t)b0 * LSEQ * HID, Weffh, beff, xib, szb);
    hipLaunchKernelGGL(k3_conv, dim3(rows / 4), dim3(256), 0, stream, xib, cw, cb, xsb);
    hipLaunchKernelGGL(k4_xdbl, dim3(rows / 64), dim3(256), 0, stream, xsb, xpw, dtg, bcb);
    hipLaunchKernelGGL(k5_scan, dim3(nb * 8), dim3(256), 0, stream,
                       dtg, xsb, szb, bcb, A_log, Dv, dtw, dtb, ysum + (size_t)b0 * DINN);
  }
  hipLaunchKernelGGL(k6_head, dim3(NB), dim3(128), 0, stream,
                     ysum, opw, fc1w, fc1b, fc2w, fc2b, out);
}

// Round 12
// 1506.689 us; speedup vs baseline: 1.0238x; 1.0238x over previous
//
#include <hip/hip_runtime.h>
#include <cstdint>
#include <cstddef>

constexpr int LSEQ = 1000;   // sequence length
constexpr int NB   = 128;    // batch
constexpr int CINP = 12;     // input channels
constexpr int HID  = 128;    // lstm hidden
constexpr int NGATE = 4 * HID;  // 512
constexpr int DMOD = 128;    // d_model
constexpr int DINN = 256;    // d_inner
constexpr int NCL  = 5;

typedef unsigned short ushort_t;
typedef _Float16 half2_t __attribute__((ext_vector_type(2)));

__device__ __forceinline__ float bf2f(ushort_t u) {
  uint32_t b = ((uint32_t)u) << 16;
  float f; __builtin_memcpy(&f, &b, 4); return f;
}
__device__ __forceinline__ ushort_t f2bf(float f) {
  uint32_t b; __builtin_memcpy(&b, &f, 4);
  uint32_t r = (b + 0x7fffu + ((b >> 16) & 1u)) >> 16;
  return (ushort_t)r;
}
__device__ __forceinline__ half2_t u2h2(uint32_t v) {
  half2_t h; __builtin_memcpy(&h, &v, 4); return h;
}
__device__ __forceinline__ uint32_t h22u(half2_t h) {
  uint32_t v; __builtin_memcpy(&v, &h, 4); return v;
}
// two bf16 packed in u32 -> two f16 packed in u32
__device__ __forceinline__ uint32_t bfpair_to_h2(uint32_t v) {
  half2_t h;
  h.x = (_Float16)bf2f((ushort_t)(v & 0xffff));
  h.y = (_Float16)bf2f((ushort_t)(v >> 16));
  return h22u(h);
}

#if __has_builtin(__builtin_amdgcn_fdot2)
__device__ __forceinline__ float FDOT2(half2_t a, half2_t b, float c) {
  return __builtin_amdgcn_fdot2(a, b, c, false);
}
#else
__device__ __forceinline__ float FDOT2(half2_t a, half2_t b, float c) {
  return c + (float)a.x * (float)b.x + (float)a.y * (float)b.y;
}
#endif

// LDS-only barrier: drains lgkmcnt but NOT vmcnt (global stores keep flowing).
__device__ __forceinline__ void bar_lgkm() {
  asm volatile("s_waitcnt lgkmcnt(0)\n\ts_barrier" ::: "memory");
}

// ---------------------------------------------------------------------------
// K0: fold input_proj into in_proj; emit Weff PRE-PACKED as f16 pairs.
__global__ __launch_bounds__(256) void k0_weff(
    const float* __restrict__ ipw, const float* __restrict__ Wp,
    const float* __restrict__ bp, uint32_t* __restrict__ Weffh,
    float* __restrict__ beff) {
  int idx = blockIdx.x * 256 + threadIdx.x;   // grid 128 blocks -> 32768
  if (idx < NGATE * 64) {
    int e = idx >> 6, j = idx & 63;
    float a0 = 0.f, a1 = 0.f;
    for (int d = 0; d < DMOD; ++d) {
      float w = ipw[e * DMOD + d];
      a0 += w * Wp[d * HID + 2 * j];
      a1 += w * Wp[d * HID + 2 * j + 1];
    }
    half2_t h; h.x = (_Float16)a0; h.y = (_Float16)a1;
    Weffh[idx] = h22u(h);
  }
  if (idx < NGATE) {
    float acc = 0.f;
    for (int d = 0; d < DMOD; ++d) acc += ipw[idx * DMOD + d] * bp[d];
    beff[idx] = acc;
  }
}

// ---------------------------------------------------------------------------
// K1: LSTM "split-gate". 256 threads; thread u (half 0) owns gate rows
//     {i=u, f=u+128}; thread u+128 (half 1) owns {g=u+256, o=u+384}.
//     NO gate gather: half1 drops tanh(g), sig(o) into a 1KB LDS buffer
//     concurrently with half0's sig(i), sig(f); one barrier; half0 finishes
//     the c/h recurrence. Critical path loses the g_sh round-trip + one
//     full nonlin serialization.
__global__ __launch_bounds__(256, 1) void k1_lstm(
    const float* __restrict__ x, const float* __restrict__ W_ih,
    const float* __restrict__ W_hh, const float* __restrict__ b_ih,
    const float* __restrict__ b_hh, ushort_t* __restrict__ hout) {
  __shared__ __align__(16) float x_sh[LSEQ * CINP];      // 48 KB
  __shared__ __align__(16) ushort_t h_sh[HID];           // f16 bits
  __shared__ float tg_sh[HID];                           // tanh(g) from half1
  __shared__ float so_sh[HID];                           // sig(o)  from half1
  const int t = threadIdx.x;          // 0..255
  const int u = t & 127;              // unit
  const int half = t >> 7;            // 0: rows {u,u+128}; 1: {u+256,u+384}
  const int rA = u + half * 256;      // i or g
  const int rB = rA + 128;            // f or o
  const int b = blockIdx.x;

  const float4* xg4 = reinterpret_cast<const float4*>(x + (size_t)b * LSEQ * CINP);
  float4* xs4 = reinterpret_cast<float4*>(x_sh);
  for (int i = t; i < LSEQ * CINP / 4; i += 256) xs4[i] = xg4[i];

  // W_hh rows rA, rB -> 64 packed f16 pairs each
  half2_t wa2[64], wb2[64];
  {
    const float4* wa4 = reinterpret_cast<const float4*>(W_hh) + rA * (HID / 4);
    const float4* wb4 = reinterpret_cast<const float4*>(W_hh) + rB * (HID / 4);
#pragma unroll
    for (int k = 0; k < HID / 4; ++k) {
      float4 v = wa4[k];
      half2_t a; a.x = (_Float16)v.x; a.y = (_Float16)v.y;
      half2_t c; c.x = (_Float16)v.z; c.y = (_Float16)v.w;
      wa2[2 * k] = a; wa2[2 * k + 1] = c;
      float4 w = wb4[k];
      half2_t d; d.x = (_Float16)w.x; d.y = (_Float16)w.y;
      half2_t e; e.x = (_Float16)w.z; e.y = (_Float16)w.w;
      wb2[2 * k] = d; wb2[2 * k + 1] = e;
    }
  }
  float wia[CINP], wib[CINP];
#pragma unroll
  for (int c = 0; c < CINP; ++c) {
    wia[c] = W_ih[rA * CINP + c];
    wib[c] = W_ih[rB * CINP + c];
  }
  const float biasA = b_ih[rA] + b_hh[rA];
  const float biasB = b_ih[rB] + b_hh[rB];

  float cstate = 0.f;
  if (t < HID) h_sh[t] = 0;
  __syncthreads();   // full barrier once (covers global->LDS staging)

  for (int l = 0; l < LSEQ; ++l) {
    const float* xr = &x_sh[l * CINP];
    float pa0 = biasA, pa1 = 0.f, pa2 = 0.f, pa3 = 0.f;
    float pb0 = biasB, pb1 = 0.f, pb2 = 0.f, pb3 = 0.f;
#pragma unroll
    for (int c = 0; c < CINP; c += 4) {
      float x0 = xr[c], x1 = xr[c + 1], x2 = xr[c + 2], x3 = xr[c + 3];
      pa0 += x0 * wia[c];     pa1 += x1 * wia[c + 1];
      pa2 += x2 * wia[c + 2]; pa3 += x3 * wia[c + 3];
      pb0 += x0 * wib[c];     pb1 += x1 * wib[c + 1];
      pb2 += x2 * wib[c + 2]; pb3 += x3 * wib[c + 3];
    }
    const uint4* h4 = reinterpret_cast<const uint4*>(h_sh);
#pragma unroll
    for (int kk = 0; kk < 16; ++kk) {
      uint4 hv = h4[kk];   // read ONCE, feeds both rows
      half2_t h0 = u2h2(hv.x), h1 = u2h2(hv.y), h2 = u2h2(hv.z), h3 = u2h2(hv.w);
      pa0 = FDOT2(h0, wa2[4 * kk],     pa0);
      pa1 = FDOT2(h1, wa2[4 * kk + 1], pa1);
      pa2 = FDOT2(h2, wa2[4 * kk + 2], pa2);
      pa3 = FDOT2(h3, wa2[4 * kk + 3], pa3);
      pb0 = FDOT2(h0, wb2[4 * kk],     pb0);
      pb1 = FDOT2(h1, wb2[4 * kk + 1], pb1);
      pb2 = FDOT2(h2, wb2[4 * kk + 2], pb2);
      pb3 = FDOT2(h3, wb2[4 * kk + 3], pb3);
    }
    float gA = (pa0 + pa1) + (pa2 + pa3);   // i (half0) or g (half1)
    float gB = (pb0 + pb1) + (pb2 + pb3);   // f (half0) or o (half1)

    float si = 0.f, sf = 0.f;
    if (half) {   // waves 2,3: tanh(g), sig(o) -> LDS
      float tg = 1.f - 2.f / (__expf(2.f * gA) + 1.f);
      float so = 1.f / (1.f + __expf(-gB));
      tg_sh[u] = tg;
      so_sh[u] = so;
    } else {      // waves 0,1: sig(i), sig(f) in registers (concurrent)
      si = 1.f / (1.f + __expf(-gA));
      sf = 1.f / (1.f + __expf(-gB));
    }
    bar_lgkm();
    if (!half) {  // waves 0,1 finish the recurrence
      cstate = sf * cstate + si * tg_sh[u];
      float th = 1.f - 2.f / (__expf(2.f * cstate) + 1.f);
      float hv = so_sh[u] * th;
      _Float16 hh = (_Float16)hv;
      ushort_t hb; __builtin_memcpy(&hb, &hh, 2);
      h_sh[u] = hb;
      hout[((size_t)b * LSEQ + l) * HID + u] = f2bf(hv);  // vmcnt never drained in-loop
    }
    bar_lgkm();
  }
}

// ---------------------------------------------------------------------------
// K2: xz = h @ Weff.T + beff via packed-f16 dot2. 64x64 tile, LDS 34 KB,
//     b64 LDS reads (stride 66 words). cols<256 -> xi; >=256 -> silu -> sz.
__global__ __launch_bounds__(256) void k2_xz(
    const ushort_t* __restrict__ hbuf, const uint32_t* __restrict__ Weffh,
    const float* __restrict__ beff, ushort_t* __restrict__ xi,
    ushort_t* __restrict__ sz) {
  constexpr int S = 66;                 // u32 stride per 64-pair row
  __shared__ __align__(16) uint32_t As[64 * S];
  __shared__ __align__(16) uint32_t Bs[64 * S];
  const int tid = threadIdx.x;
  const size_t m0 = (size_t)blockIdx.x * 64;
  const int n0 = blockIdx.y * 64;

  const uint4* h4g = reinterpret_cast<const uint4*>(hbuf);
  for (int i = tid; i < 64 * 16; i += 256) {
    int row = i >> 4, c = i & 15;
    uint4 v = h4g[(m0 + row) * 16 + c];
    uint32_t* p = &As[row * S + c * 4];
    p[0] = bfpair_to_h2(v.x); p[1] = bfpair_to_h2(v.y);
    p[2] = bfpair_to_h2(v.z); p[3] = bfpair_to_h2(v.w);
  }
  const uint4* w4g = reinterpret_cast<const uint4*>(Weffh);
  for (int i = tid; i < 64 * 16; i += 256) {
    int row = i >> 4, c = i & 15;
    uint4 v = w4g[(size_t)(n0 + row) * 16 + c];
    uint32_t* p = &Bs[row * S + c * 4];
    p[0] = v.x; p[1] = v.y; p[2] = v.z; p[3] = v.w;
  }
  __syncthreads();

  const int tx = tid & 15, ty = tid >> 4;
  float acc[4][4] = {};
  const uint32_t* ap = &As[(ty * 4) * S];
  const uint32_t* bp = &Bs[(tx * 4) * S];
#pragma unroll 4
  for (int kk = 0; kk < 32; ++kk) {      // 2 k-pairs (4 k) per iter
    uint2 a0 = *reinterpret_cast<const uint2*>(&ap[kk * 2]);
    uint2 a1 = *reinterpret_cast<const uint2*>(&ap[S + kk * 2]);
    uint2 a2 = *reinterpret_cast<const uint2*>(&ap[2 * S + kk * 2]);
    uint2 a3 = *reinterpret_cast<const uint2*>(&ap[3 * S + kk * 2]);
    uint2 b0 = *reinterpret_cast<const uint2*>(&bp[kk * 2]);
    uint2 b1 = *reinterpret_cast<const uint2*>(&bp[S + kk * 2]);
    uint2 b2 = *reinterpret_cast<const uint2*>(&bp[2 * S + kk * 2]);
    uint2 b3 = *reinterpret_cast<const uint2*>(&bp[3 * S + kk * 2]);
    acc[0][0] = FDOT2(u2h2(a0.x), u2h2(b0.x), acc[0][0]);
    acc[0][1] = FDOT2(u2h2(a0.x), u2h2(b1.x), acc[0][1]);
    acc[0][2] = FDOT2(u2h2(a0.x), u2h2(b2.x), acc[0][2]);
    acc[0][3] = FDOT2(u2h2(a0.x), u2h2(b3.x), acc[0][3]);
    acc[1][0] = FDOT2(u2h2(a1.x), u2h2(b0.x), acc[1][0]);
    acc[1][1] = FDOT2(u2h2(a1.x), u2h2(b1.x), acc[1][1]);
    acc[1][2] = FDOT2(u2h2(a1.x), u2h2(b2.x), acc[1][2]);
    acc[1][3] = FDOT2(u2h2(a1.x), u2h2(b3.x), acc[1][3]);
    acc[2][0] = FDOT2(u2h2(a2.x), u2h2(b0.x), acc[2][0]);
    acc[2][1] = FDOT2(u2h2(a2.x), u2h2(b1.x), acc[2][1]);
    acc[2][2] = FDOT2(u2h2(a2.x), u2h2(b2.x), acc[2][2]);
    acc[2][3] = FDOT2(u2h2(a2.x), u2h2(b3.x), acc[2][3]);
    acc[3][0] = FDOT2(u2h2(a3.x), u2h2(b0.x), acc[3][0]);
    acc[3][1] = FDOT2(u2h2(a3.x), u2h2(b1.x), acc[3][1]);
    acc[3][2] = FDOT2(u2h2(a3.x), u2h2(b2.x), acc[3][2]);
    acc[3][3] = FDOT2(u2h2(a3.x), u2h2(b3.x), acc[3][3]);
    acc[0][0] = FDOT2(u2h2(a0.y), u2h2(b0.y), acc[0][0]);
    acc[0][1] = FDOT2(u2h2(a0.y), u2h2(b1.y), acc[0][1]);
    acc[0][2] = FDOT2(u2h2(a0.y), u2h2(b2.y), acc[0][2]);
    acc[0][3] = FDOT2(u2h2(a0.y), u2h2(b3.y), acc[0][3]);
    acc[1][0] = FDOT2(u2h2(a1.y), u2h2(b0.y), acc[1][0]);
    acc[1][1] = FDOT2(u2h2(a1.y), u2h2(b1.y), acc[1][1]);
    acc[1][2] = FDOT2(u2h2(a1.y), u2h2(b2.y), acc[1][2]);
    acc[1][3] = FDOT2(u2h2(a1.y), u2h2(b3.y), acc[1][3]);
    acc[2][0] = FDOT2(u2h2(a2.y), u2h2(b0.y), acc[2][0]);
    acc[2][1] = FDOT2(u2h2(a2.y), u2h2(b1.y), acc[2][1]);
    acc[2][2] = FDOT2(u2h2(a2.y), u2h2(b2.y), acc[2][2]);
    acc[2][3] = FDOT2(u2h2(a2.y), u2h2(b3.y), acc[2][3]);
    acc[3][0] = FDOT2(u2h2(a3.y), u2h2(b0.y), acc[3][0]);
    acc[3][1] = FDOT2(u2h2(a3.y), u2h2(b1.y), acc[3][1]);
    acc[3][2] = FDOT2(u2h2(a3.y), u2h2(b2.y), acc[3][2]);
    acc[3][3] = FDOT2(u2h2(a3.y), u2h2(b3.y), acc[3][3]);
  }

  const int col = n0 + tx * 4;
  float4 be = *reinterpret_cast<const float4*>(&beff[col]);
#pragma unroll
  for (int i = 0; i < 4; ++i) {
    size_t row = m0 + ty * 4 + i;
    float v0 = acc[i][0] + be.x, v1 = acc[i][1] + be.y;
    float v2 = acc[i][2] + be.z, v3 = acc[i][3] + be.w;
    ushort4 o;
    if (n0 < 256) {
      o.x = f2bf(v0); o.y = f2bf(v1); o.z = f2bf(v2); o.w = f2bf(v3);
      *reinterpret_cast<ushort4*>(&xi[row * 256 + col]) = o;
    } else {
      o.x = f2bf(v0 / (1.f + __expf(-v0)));
      o.y = f2bf(v1 / (1.f + __expf(-v1)));
      o.z = f2bf(v2 / (1.f + __expf(-v2)));
      o.w = f2bf(v3 / (1.f + __expf(-v3)));
      *reinterpret_cast<ushort4*>(&sz[row * 256 + (col - 256)]) = o;
    }
  }
}

// ---------------------------------------------------------------------------
// K3: causal depthwise conv (DC=4) + silu. 4 timesteps per block, register
//     halo. Blocks never straddle a batch boundary (1000 % 4 == 0).
__global__ __launch_bounds__(256) void k3_conv(
    const ushort_t* __restrict__ xi, const float* __restrict__ cw,
    const float* __restrict__ cb, ushort_t* __restrict__ xs) {
  const int d = threadIdx.x;
  const size_t bl0 = (size_t)blockIdx.x * 4;
  const int l0 = (int)(bl0 % LSEQ);
  float w0 = cw[d * 4], w1 = cw[d * 4 + 1], w2 = cw[d * 4 + 2], w3 = cw[d * 4 + 3];
  const float cbv = cb[d];
  const ushort_t* p = &xi[bl0 * 256 + d];
  float xm3 = (l0 >= 3) ? bf2f(p[-768]) : 0.f;
  float xm2 = (l0 >= 2) ? bf2f(p[-512]) : 0.f;
  float xm1 = (l0 >= 1) ? bf2f(p[-256]) : 0.f;
  float x0 = bf2f(p[0]);
  float x1 = bf2f(p[256]);
  float x2 = bf2f(p[512]);
  float x3 = bf2f(p[768]);
  float o0 = cbv + w0 * xm3 + w1 * xm2 + w2 * xm1 + w3 * x0;
  float o1 = cbv + w0 * xm2 + w1 * xm1 + w2 * x0 + w3 * x1;
  float o2 = cbv + w0 * xm1 + w1 * x0 + w2 * x1 + w3 * x2;
  float o3 = cbv + w0 * x0 + w1 * x1 + w2 * x2 + w3 * x3;
  ushort_t* q = &xs[bl0 * 256 + d];
  q[0]   = f2bf(o0 / (1.f + __expf(-o0)));
  q[256] = f2bf(o1 / (1.f + __expf(-o1)));
  q[512] = f2bf(o2 / (1.f + __expf(-o2)));
  q[768] = f2bf(o3 / (1.f + __expf(-o3)));
}

// ---------------------------------------------------------------------------
// K4: x_dbl = xs @ x_proj_w.T (N=40) via packed f16 dot2.
//     b64 LDS reads: stride 134 (even -> 8B aligned rows); 11 reads per 2 K.
__global__ __launch_bounds__(256) void k4_xdbl(
    const ushort_t* __restrict__ xs, const float* __restrict__ xpw,
    float* __restrict__ dtg, float* __restrict__ bc) {
  constexpr int XSTR = 134;
  __shared__ __align__(16) uint32_t xsh[64 * XSTR];
  __shared__ __align__(16) uint32_t wsh[40 * 128];
  const int tid = threadIdx.x;
  const size_t r0 = (size_t)blockIdx.x * 64;

  for (int i = tid; i < 64 * 128; i += 256) {
    int row = i >> 7, kk = i & 127;
    uint32_t v = *reinterpret_cast<const uint32_t*>(&xs[(r0 + row) * 256 + kk * 2]);
    xsh[row * XSTR + kk] = bfpair_to_h2(v);
  }
  for (int i = tid; i < 40 * 128; i += 256) {
    int c = i >> 7, kk = i & 127;
    half2_t h;
    h.x = (_Float16)xpw[c * 256 + kk * 2];
    h.y = (_Float16)xpw[c * 256 + kk * 2 + 1];
    wsh[i] = h22u(h);
  }
  __syncthreads();

  const int row = tid & 63;
  const int cg = tid >> 6;   // wave-uniform
  float acc[10] = {};
  for (int kk2 = 0; kk2 < 64; ++kk2) {
    uint2 xv = *reinterpret_cast<const uint2*>(&xsh[row * XSTR + kk2 * 2]);
    half2_t x0 = u2h2(xv.x), x1 = u2h2(xv.y);
#pragma unroll
    for (int i = 0; i < 10; ++i) {
      uint2 wv = *reinterpret_cast<const uint2*>(&wsh[(cg + 4 * i) * 128 + kk2 * 2]);
      acc[i] = FDOT2(x0, u2h2(wv.x), acc[i]);
      acc[i] = FDOT2(x1, u2h2(wv.y), acc[i]);
    }
  }
#pragma unroll
  for (int i = 0; i < 10; ++i) {
    int c = cg + 4 * i;
    if (c < 8) dtg[(r0 + row) * 8 + c] = acc[i];
    else bc[(r0 + row) * 32 + (c - 8)] = acc[i];
  }
}

// ---------------------------------------------------------------------------
// K5: selective scan. 8 threads per (b,d), 2 states each. NO in-loop shfl:
//     z is group-uniform, so each thread accumulates y_part*z privately and
//     the 8-lane reduction happens ONCE after the loop. D-term via accD.
__global__ __launch_bounds__(256) void k5_scan(
    const float* __restrict__ dtg, const ushort_t* __restrict__ xs,
    const ushort_t* __restrict__ sz, const float* __restrict__ bc,
    const float* __restrict__ A_log, const float* __restrict__ Dv,
    const float* __restrict__ dtw, const float* __restrict__ dtb,
    float* __restrict__ ysum) {
  const int b  = blockIdx.x >> 3;
  const int d  = ((blockIdx.x & 7) << 5) + (threadIdx.x >> 3);  // 0..255
  const int sg = threadIdx.x & 7;                                // 2 states each

  const float Aa0 = -__expf(A_log[d * 16 + sg * 2]);
  const float Aa1 = -__expf(A_log[d * 16 + sg * 2 + 1]);
  float w8[8];
#pragma unroll
  for (int r = 0; r < 8; ++r) w8[r] = dtw[d * 8 + r];
  const float db = dtb[d];
  const float DD = Dv[d];

  float h0 = 0.f, h1 = 0.f;
  float acc = 0.f, accD = 0.f;
  const size_t base = (size_t)b * LSEQ;

  float4 dta_c = *reinterpret_cast<const float4*>(&dtg[base * 8]);
  float4 dtb_c = *reinterpret_cast<const float4*>(&dtg[base * 8 + 4]);
  float  xv_c  = bf2f(xs[base * 256 + d]);
  float  zv_c  = bf2f(sz[base * 256 + d]);
  float2 bv_c  = *reinterpret_cast<const float2*>(&bc[base * 32 + sg * 2]);
  float2 cv_c  = *reinterpret_cast<const float2*>(&bc[base * 32 + 16 + sg * 2]);

  for (int l = 0; l < LSEQ; ++l) {
    const size_t nrow = base + ((l + 1 < LSEQ) ? (l + 1) : l);
    float4 dta_n = *reinterpret_cast<const float4*>(&dtg[nrow * 8]);
    float4 dtb_n = *reinterpret_cast<const float4*>(&dtg[nrow * 8 + 4]);
    float  xv_n  = bf2f(xs[nrow * 256 + d]);
    float  zv_n  = bf2f(sz[nrow * 256 + d]);
    float2 bv_n  = *reinterpret_cast<const float2*>(&bc[nrow * 32 + sg * 2]);
    float2 cv_n  = *reinterpret_cast<const float2*>(&bc[nrow * 32 + 16 + sg * 2]);

    float a = db + dta_c.x * w8[0] + dta_c.y * w8[1] + dta_c.z * w8[2] + dta_c.w * w8[3]
                 + dtb_c.x * w8[4] + dtb_c.y * w8[5] + dtb_c.z * w8[6] + dtb_c.w * w8[7];
    float dl = (a > 20.f) ? a : __logf(1.f + __expf(a));
    float dx = dl * xv_c;
    h0 = __expf(dl * Aa0) * h0 + dx * bv_c.x;
    h1 = __expf(dl * Aa1) * h1 + dx * bv_c.y;
    acc += (h0 * cv_c.x + h1 * cv_c.y) * zv_c;   // partial y * z (z group-uniform)
    accD += xv_c * zv_c;                          // D-term, folded once at end

    dta_c = dta_n; dtb_c = dtb_n;
    xv_c = xv_n; zv_c = zv_n; bv_c = bv_n; cv_c = cv_n;
  }
  if (sg == 0) acc += DD * accD;
  acc += __shfl_xor(acc, 1);
  acc += __shfl_xor(acc, 2);
  acc += __shfl_xor(acc, 4);
  if (sg == 0) ysum[b * 256 + d] = acc;
}

// ---------------------------------------------------------------------------
// K6: head. pooled = ysum@opw.T/L ; fc1+relu ; fc2.
__global__ __launch_bounds__(128) void k6_head(
    const float* __restrict__ ysum, const float* __restrict__ opw,
    const float* __restrict__ fc1w, const float* __restrict__ fc1b,
    const float* __restrict__ fc2w, const float* __restrict__ fc2b,
    float* __restrict__ out) {
  __shared__ float ys[256], pool[128], fcs[128];
  const int b = blockIdx.x, t = threadIdx.x;
  for (int i = t; i < 256; i += 128) ys[i] = ysum[b * 256 + i];
  __syncthreads();
  float a = 0.f;
  for (int e = 0; e < 256; ++e) a += opw[t * 256 + e] * ys[e];
  pool[t] = a * (1.0f / (float)LSEQ);
  __syncthreads();
  float a1 = fc1b[t];
  for (int d2 = 0; d2 < 128; ++d2) a1 += fc1w[t * 128 + d2] * pool[d2];
  fcs[t] = fmaxf(a1, 0.f);
  __syncthreads();
  if (t < NCL) {
    float o = fc2b[t];
    for (int f = 0; f < 128; ++f) o += fc2w[t * 128 + f] * fcs[f];
    out[b * NCL + t] = o;
  }
}

// ---------------------------------------------------------------------------
extern "C" void kernel_launch(void* const* d_in, const int* in_sizes, int n_in,
                              void* d_out, int out_size, void* d_ws, size_t ws_size,
                              hipStream_t stream) {
  const float* x     = (const float*)d_in[0];
  const float* W_ih  = (const float*)d_in[1];
  const float* W_hh  = (const float*)d_in[2];
  const float* b_ih  = (const float*)d_in[3];
  const float* b_hh  = (const float*)d_in[4];
  const float* Wp    = (const float*)d_in[5];
  const float* bp    = (const float*)d_in[6];
  const float* ipw   = (const float*)d_in[7];
  const float* cw    = (const float*)d_in[8];
  const float* cb    = (const float*)d_in[9];
  const float* xpw   = (const float*)d_in[10];
  const float* dtw   = (const float*)d_in[11];
  const float* dtb   = (const float*)d_in[12];
  const float* A_log = (const float*)d_in[13];
  const float* Dv    = (const float*)d_in[14];
  const float* opw   = (const float*)d_in[15];
  const float* fc1w  = (const float*)d_in[16];
  const float* fc1b  = (const float*)d_in[17];
  const float* fc2w  = (const float*)d_in[18];
  const float* fc2b  = (const float*)d_in[19];
  float* out = (float*)d_out;

  const size_t A_WEFF = 131072;                          // packed f16 pairs
  const size_t A_BEFF = 4096, A_YSUM = 131072;
  const size_t A_HBUF = (size_t)NB * LSEQ * HID * 2;     // 32.77 MB
  const size_t A_XS   = (size_t)NB * LSEQ * DINN * 2;    // 65.54 MB
  const size_t A_SZ   = A_XS;                            // 65.54 MB
  const size_t A_DT   = (size_t)NB * LSEQ * 8 * 4;       // 4.10 MB
  const size_t A_BC   = (size_t)NB * LSEQ * 32 * 4;      // 16.38 MB
  const size_t FIXED_WIDE = A_WEFF + A_BEFF + A_YSUM + A_HBUF + A_XS + A_SZ + A_DT + A_BC;

  int nb_w = 0;
  for (int c = 128; c >= 8; c >>= 1) {
    if (FIXED_WIDE + (size_t)c * LSEQ * DINN * 2 <= ws_size) { nb_w = c; break; }
  }

  if (nb_w > 0) {
    char* p = (char*)d_ws;
    uint32_t* Weffh = (uint32_t*)p; p += A_WEFF;
    float*    beff = (float*)p;    p += A_BEFF;
    float*    ysum = (float*)p;    p += A_YSUM;
    ushort_t* hbuf = (ushort_t*)p; p += A_HBUF;
    ushort_t* xsb  = (ushort_t*)p; p += A_XS;
    ushort_t* szb  = (ushort_t*)p; p += A_SZ;
    float*    dtg  = (float*)p;    p += A_DT;
    float*    bcb  = (float*)p;    p += A_BC;
    ushort_t* xib  = (ushort_t*)p;

    hipLaunchKernelGGL(k0_weff, dim3(128), dim3(256), 0, stream, ipw, Wp, bp, Weffh, beff);
    hipLaunchKernelGGL(k1_lstm, dim3(NB), dim3(256), 0, stream, x, W_ih, W_hh, b_ih, b_hh, hbuf);

    for (int b0 = 0; b0 < NB; b0 += nb_w) {
      const int rows = nb_w * LSEQ;
      const size_t ro = (size_t)b0 * LSEQ;
      hipLaunchKernelGGL(k2_xz, dim3(rows / 64, 8), dim3(256), 0, stream,
                         hbuf + ro * HID, Weffh, beff, xib, szb + ro * DINN);
      hipLaunchKernelGGL(k3_conv, dim3(rows / 4), dim3(256), 0, stream,
                         xib, cw, cb, xsb + ro * DINN);
      hipLaunchKernelGGL(k4_xdbl, dim3(rows / 64), dim3(256), 0, stream,
                         xsb + ro * DINN, xpw, dtg + ro * 8, bcb + ro * 32);
    }
    hipLaunchKernelGGL(k5_scan, dim3(NB * 8), dim3(256), 0, stream,
                       dtg, xsb, szb, bcb, A_log, Dv, dtw, dtb, ysum);
    hipLaunchKernelGGL(k6_head, dim3(NB), dim3(128), 0, stream,
                       ysum, opw, fc1w, fc1b, fc2w, fc2b, out);
    return;
  }

  // --- fallback: fully chunked ---
  const size_t FIXED = A_WEFF + A_BEFF + A_YSUM + A_HBUF;
  const size_t PERB = (size_t)LSEQ * DINN * 2 * 3 + (size_t)LSEQ * 8 * 4 + (size_t)LSEQ * 32 * 4;
  int nb = 8;
  for (int c = 128; c >= 8; c >>= 1) {
    if (FIXED + (size_t)c * PERB <= ws_size) { nb = c; break; }
  }
  char* p = (char*)d_ws;
  uint32_t* Weffh = (uint32_t*)p; p += A_WEFF;
  float*    beff = (float*)p;    p += A_BEFF;
  float*    ysum = (float*)p;    p += A_YSUM;
  ushort_t* hbuf = (ushort_t*)p; p += A_HBUF;
  ushort_t* xib  = (ushort_t*)p; p += (size_t)nb * LSEQ * DINN * 2;
  ushort_t* szb  = (ushort_t*)p; p += (size_t)nb * LSEQ * DINN * 2;
  ushort_t* xsb  = (ushort_t*)p; p += (size_t)nb * LSEQ * DINN * 2;
  float*    dtg  = (float*)p;    p += (size_t)nb * LSEQ * 8 * 4;
  float*    bcb  = (float*)p;

  hipLaunchKernelGGL(k0_weff, dim3(128), dim3(256), 0, stream, ipw, Wp, bp, Weffh, beff);
  hipLaunchKernelGGL(k1_lstm, dim3(NB), dim3(256), 0, stream, x, W_ih, W_hh, b_ih, b_hh, hbuf);
  for (int b0 = 0; b0 < NB; b0 += nb) {
    const int rows = nb * LSEQ;
    hipLaunchKernelGGL(k2_xz, dim3(rows / 64, 8), dim3(256), 0, stream,
                       hbuf + (size_t)b0 * LSEQ * HID, Weffh, beff, xib, szb);
    hipLaunchKernelGGL(k3_conv, dim3(rows / 4), dim3(256), 0, stream, xib, cw, cb, xsb);
    hipLaunchKernelGGL(k4_xdbl, dim3(rows / 64), dim3(256), 0, stream, xsb, xpw, dtg, bcb);
    hipLaunchKernelGGL(k5_scan, dim3(nb * 8), dim3(256), 0, stream,
                       dtg, xsb, szb, bcb, A_log, Dv, dtw, dtb, ysum + (size_t)b0 * DINN);
  }
  hipLaunchKernelGGL(k6_head, dim3(NB), dim3(128), 0, stream,
                     ysum, opw, fc1w, fc1b, fc2w, fc2b, out);
}

// Round 13
// 1506.008 us; speedup vs baseline: 1.0243x; 1.0005x over previous
//
#include <hip/hip_runtime.h>
#include <cstdint>
#include <cstddef>

constexpr int LSEQ = 1000;   // sequence length
constexpr int NB   = 128;    // batch
constexpr int CINP = 12;     // input channels
constexpr int HID  = 128;    // lstm hidden
constexpr int NGATE = 4 * HID;  // 512
constexpr int DMOD = 128;    // d_model
constexpr int DINN = 256;    // d_inner
constexpr int NCL  = 5;

typedef unsigned short ushort_t;
typedef _Float16 half2_t __attribute__((ext_vector_type(2)));

__device__ __forceinline__ float bf2f(ushort_t u) {
  uint32_t b = ((uint32_t)u) << 16;
  float f; __builtin_memcpy(&f, &b, 4); return f;
}
__device__ __forceinline__ ushort_t f2bf(float f) {
  uint32_t b; __builtin_memcpy(&b, &f, 4);
  uint32_t r = (b + 0x7fffu + ((b >> 16) & 1u)) >> 16;
  return (ushort_t)r;
}
__device__ __forceinline__ half2_t u2h2(uint32_t v) {
  half2_t h; __builtin_memcpy(&h, &v, 4); return h;
}
__device__ __forceinline__ uint32_t h22u(half2_t h) {
  uint32_t v; __builtin_memcpy(&v, &h, 4); return v;
}
// two bf16 packed in u32 -> two f16 packed in u32
__device__ __forceinline__ uint32_t bfpair_to_h2(uint32_t v) {
  half2_t h;
  h.x = (_Float16)bf2f((ushort_t)(v & 0xffff));
  h.y = (_Float16)bf2f((ushort_t)(v >> 16));
  return h22u(h);
}

#if __has_builtin(__builtin_amdgcn_fdot2)
__device__ __forceinline__ float FDOT2(half2_t a, half2_t b, float c) {
  return __builtin_amdgcn_fdot2(a, b, c, false);
}
#else
__device__ __forceinline__ float FDOT2(half2_t a, half2_t b, float c) {
  return c + (float)a.x * (float)b.x + (float)a.y * (float)b.y;
}
#endif

// LDS-only barrier: drains lgkmcnt but NOT vmcnt (global stores keep flowing).
__device__ __forceinline__ void bar_lgkm() {
  asm volatile("s_waitcnt lgkmcnt(0)\n\ts_barrier" ::: "memory");
}

// ---------------------------------------------------------------------------
// K0: fold input_proj into in_proj; emit Weff PRE-PACKED as f16 pairs.
__global__ __launch_bounds__(256) void k0_weff(
    const float* __restrict__ ipw, const float* __restrict__ Wp,
    const float* __restrict__ bp, uint32_t* __restrict__ Weffh,
    float* __restrict__ beff) {
  int idx = blockIdx.x * 256 + threadIdx.x;   // grid 128 blocks -> 32768
  if (idx < NGATE * 64) {
    int e = idx >> 6, j = idx & 63;
    float a0 = 0.f, a1 = 0.f;
    for (int d = 0; d < DMOD; ++d) {
      float w = ipw[e * DMOD + d];
      a0 += w * Wp[d * HID + 2 * j];
      a1 += w * Wp[d * HID + 2 * j + 1];
    }
    half2_t h; h.x = (_Float16)a0; h.y = (_Float16)a1;
    Weffh[idx] = h22u(h);
  }
  if (idx < NGATE) {
    float acc = 0.f;
    for (int d = 0; d < DMOD; ++d) acc += ipw[idx * DMOD + d] * bp[d];
    beff[idx] = acc;
  }
}

// ---------------------------------------------------------------------------
// K1: LSTM "split-gate" (best measured: 748 us). 256 threads; thread u
//     (half 0) owns gate rows {i=u, f=u+128}; thread u+128 (half 1) owns
//     {g=u+256, o=u+384}. No gate gather; lgkm-only barriers.
__global__ __launch_bounds__(256, 1) void k1_lstm(
    const float* __restrict__ x, const float* __restrict__ W_ih,
    const float* __restrict__ W_hh, const float* __restrict__ b_ih,
    const float* __restrict__ b_hh, ushort_t* __restrict__ hout) {
  __shared__ __align__(16) float x_sh[LSEQ * CINP];      // 48 KB
  __shared__ __align__(16) ushort_t h_sh[HID];           // f16 bits
  __shared__ float tg_sh[HID];                           // tanh(g) from half1
  __shared__ float so_sh[HID];                           // sig(o)  from half1
  const int t = threadIdx.x;          // 0..255
  const int u = t & 127;              // unit
  const int half = t >> 7;            // 0: rows {u,u+128}; 1: {u+256,u+384}
  const int rA = u + half * 256;      // i or g
  const int rB = rA + 128;            // f or o
  const int b = blockIdx.x;

  const float4* xg4 = reinterpret_cast<const float4*>(x + (size_t)b * LSEQ * CINP);
  float4* xs4 = reinterpret_cast<float4*>(x_sh);
  for (int i = t; i < LSEQ * CINP / 4; i += 256) xs4[i] = xg4[i];

  half2_t wa2[64], wb2[64];
  {
    const float4* wa4 = reinterpret_cast<const float4*>(W_hh) + rA * (HID / 4);
    const float4* wb4 = reinterpret_cast<const float4*>(W_hh) + rB * (HID / 4);
#pragma unroll
    for (int k = 0; k < HID / 4; ++k) {
      float4 v = wa4[k];
      half2_t a; a.x = (_Float16)v.x; a.y = (_Float16)v.y;
      half2_t c; c.x = (_Float16)v.z; c.y = (_Float16)v.w;
      wa2[2 * k] = a; wa2[2 * k + 1] = c;
      float4 w = wb4[k];
      half2_t d; d.x = (_Float16)w.x; d.y = (_Float16)w.y;
      half2_t e; e.x = (_Float16)w.z; e.y = (_Float16)w.w;
      wb2[2 * k] = d; wb2[2 * k + 1] = e;
    }
  }
  float wia[CINP], wib[CINP];
#pragma unroll
  for (int c = 0; c < CINP; ++c) {
    wia[c] = W_ih[rA * CINP + c];
    wib[c] = W_ih[rB * CINP + c];
  }
  const float biasA = b_ih[rA] + b_hh[rA];
  const float biasB = b_ih[rB] + b_hh[rB];

  float cstate = 0.f;
  if (t < HID) h_sh[t] = 0;
  __syncthreads();

  for (int l = 0; l < LSEQ; ++l) {
    const float* xr = &x_sh[l * CINP];
    float pa0 = biasA, pa1 = 0.f, pa2 = 0.f, pa3 = 0.f;
    float pb0 = biasB, pb1 = 0.f, pb2 = 0.f, pb3 = 0.f;
#pragma unroll
    for (int c = 0; c < CINP; c += 4) {
      float x0 = xr[c], x1 = xr[c + 1], x2 = xr[c + 2], x3 = xr[c + 3];
      pa0 += x0 * wia[c];     pa1 += x1 * wia[c + 1];
      pa2 += x2 * wia[c + 2]; pa3 += x3 * wia[c + 3];
      pb0 += x0 * wib[c];     pb1 += x1 * wib[c + 1];
      pb2 += x2 * wib[c + 2]; pb3 += x3 * wib[c + 3];
    }
    const uint4* h4 = reinterpret_cast<const uint4*>(h_sh);
#pragma unroll
    for (int kk = 0; kk < 16; ++kk) {
      uint4 hv = h4[kk];
      half2_t h0 = u2h2(hv.x), h1 = u2h2(hv.y), h2 = u2h2(hv.z), h3 = u2h2(hv.w);
      pa0 = FDOT2(h0, wa2[4 * kk],     pa0);
      pa1 = FDOT2(h1, wa2[4 * kk + 1], pa1);
      pa2 = FDOT2(h2, wa2[4 * kk + 2], pa2);
      pa3 = FDOT2(h3, wa2[4 * kk + 3], pa3);
      pb0 = FDOT2(h0, wb2[4 * kk],     pb0);
      pb1 = FDOT2(h1, wb2[4 * kk + 1], pb1);
      pb2 = FDOT2(h2, wb2[4 * kk + 2], pb2);
      pb3 = FDOT2(h3, wb2[4 * kk + 3], pb3);
    }
    float gA = (pa0 + pa1) + (pa2 + pa3);
    float gB = (pb0 + pb1) + (pb2 + pb3);

    float si = 0.f, sf = 0.f;
    if (half) {
      float tg = 1.f - 2.f / (__expf(2.f * gA) + 1.f);
      float so = 1.f / (1.f + __expf(-gB));
      tg_sh[u] = tg;
      so_sh[u] = so;
    } else {
      si = 1.f / (1.f + __expf(-gA));
      sf = 1.f / (1.f + __expf(-gB));
    }
    bar_lgkm();
    if (!half) {
      cstate = sf * cstate + si * tg_sh[u];
      float th = 1.f - 2.f / (__expf(2.f * cstate) + 1.f);
      float hv = so_sh[u] * th;
      _Float16 hh = (_Float16)hv;
      ushort_t hb; __builtin_memcpy(&hb, &hh, 2);
      h_sh[u] = hb;
      hout[((size_t)b * LSEQ + l) * HID + u] = f2bf(hv);
    }
    bar_lgkm();
  }
}

// ---------------------------------------------------------------------------
// K2f: xz = h @ Weff.T + beff, FUSED with causal conv+silu (xi never hits
//      HBM). n0<256: compute tile + 3-row halo, stage fp32 xz in reused
//      As/Bs LDS, conv+silu -> xs. n0>=256: silu -> sz.
__global__ __launch_bounds__(256) void k2f(
    const ushort_t* __restrict__ hbuf, const uint32_t* __restrict__ Weffh,
    const float* __restrict__ beff, const float* __restrict__ cw,
    const float* __restrict__ cb, ushort_t* __restrict__ xs,
    ushort_t* __restrict__ sz) {
  constexpr int S = 66;                        // u32 stride per 64-pair row
  __shared__ __align__(16) uint32_t smem[2 * 64 * S];   // 33,792 B
  uint32_t* As = smem;
  uint32_t* Bs = smem + 64 * S;
  const int tid = threadIdx.x;
  const size_t m0 = (size_t)blockIdx.x * 64;
  const int n0 = blockIdx.y * 64;

  const uint4* h4g = reinterpret_cast<const uint4*>(hbuf);
  for (int i = tid; i < 64 * 16; i += 256) {
    int row = i >> 4, c = i & 15;
    uint4 v = h4g[(m0 + row) * 16 + c];
    uint32_t* p = &As[row * S + c * 4];
    p[0] = bfpair_to_h2(v.x); p[1] = bfpair_to_h2(v.y);
    p[2] = bfpair_to_h2(v.z); p[3] = bfpair_to_h2(v.w);
  }
  const uint4* w4g = reinterpret_cast<const uint4*>(Weffh);
  for (int i = tid; i < 64 * 16; i += 256) {
    int row = i >> 4, c = i & 15;
    uint4 v = w4g[(size_t)(n0 + row) * 16 + c];
    uint32_t* p = &Bs[row * S + c * 4];
    p[0] = v.x; p[1] = v.y; p[2] = v.z; p[3] = v.w;
  }
  __syncthreads();

  const int tx = tid & 15, ty = tid >> 4;
  float acc[4][4] = {};
  {
    const uint32_t* ap = &As[(ty * 4) * S];
    const uint32_t* bp = &Bs[(tx * 4) * S];
#pragma unroll 4
    for (int kk = 0; kk < 32; ++kk) {
      uint2 a0 = *reinterpret_cast<const uint2*>(&ap[kk * 2]);
      uint2 a1 = *reinterpret_cast<const uint2*>(&ap[S + kk * 2]);
      uint2 a2 = *reinterpret_cast<const uint2*>(&ap[2 * S + kk * 2]);
      uint2 a3 = *reinterpret_cast<const uint2*>(&ap[3 * S + kk * 2]);
      uint2 b0 = *reinterpret_cast<const uint2*>(&bp[kk * 2]);
      uint2 b1 = *reinterpret_cast<const uint2*>(&bp[S + kk * 2]);
      uint2 b2 = *reinterpret_cast<const uint2*>(&bp[2 * S + kk * 2]);
      uint2 b3 = *reinterpret_cast<const uint2*>(&bp[3 * S + kk * 2]);
      acc[0][0] = FDOT2(u2h2(a0.x), u2h2(b0.x), acc[0][0]);
      acc[0][1] = FDOT2(u2h2(a0.x), u2h2(b1.x), acc[0][1]);
      acc[0][2] = FDOT2(u2h2(a0.x), u2h2(b2.x), acc[0][2]);
      acc[0][3] = FDOT2(u2h2(a0.x), u2h2(b3.x), acc[0][3]);
      acc[1][0] = FDOT2(u2h2(a1.x), u2h2(b0.x), acc[1][0]);
      acc[1][1] = FDOT2(u2h2(a1.x), u2h2(b1.x), acc[1][1]);
      acc[1][2] = FDOT2(u2h2(a1.x), u2h2(b2.x), acc[1][2]);
      acc[1][3] = FDOT2(u2h2(a1.x), u2h2(b3.x), acc[1][3]);
      acc[2][0] = FDOT2(u2h2(a2.x), u2h2(b0.x), acc[2][0]);
      acc[2][1] = FDOT2(u2h2(a2.x), u2h2(b1.x), acc[2][1]);
      acc[2][2] = FDOT2(u2h2(a2.x), u2h2(b2.x), acc[2][2]);
      acc[2][3] = FDOT2(u2h2(a2.x), u2h2(b3.x), acc[2][3]);
      acc[3][0] = FDOT2(u2h2(a3.x), u2h2(b0.x), acc[3][0]);
      acc[3][1] = FDOT2(u2h2(a3.x), u2h2(b1.x), acc[3][1]);
      acc[3][2] = FDOT2(u2h2(a3.x), u2h2(b2.x), acc[3][2]);
      acc[3][3] = FDOT2(u2h2(a3.x), u2h2(b3.x), acc[3][3]);
      acc[0][0] = FDOT2(u2h2(a0.y), u2h2(b0.y), acc[0][0]);
      acc[0][1] = FDOT2(u2h2(a0.y), u2h2(b1.y), acc[0][1]);
      acc[0][2] = FDOT2(u2h2(a0.y), u2h2(b2.y), acc[0][2]);
      acc[0][3] = FDOT2(u2h2(a0.y), u2h2(b3.y), acc[0][3]);
      acc[1][0] = FDOT2(u2h2(a1.y), u2h2(b0.y), acc[1][0]);
      acc[1][1] = FDOT2(u2h2(a1.y), u2h2(b1.y), acc[1][1]);
      acc[1][2] = FDOT2(u2h2(a1.y), u2h2(b2.y), acc[1][2]);
      acc[1][3] = FDOT2(u2h2(a1.y), u2h2(b3.y), acc[1][3]);
      acc[2][0] = FDOT2(u2h2(a2.y), u2h2(b0.y), acc[2][0]);
      acc[2][1] = FDOT2(u2h2(a2.y), u2h2(b1.y), acc[2][1]);
      acc[2][2] = FDOT2(u2h2(a2.y), u2h2(b2.y), acc[2][2]);
      acc[2][3] = FDOT2(u2h2(a2.y), u2h2(b3.y), acc[2][3]);
      acc[3][0] = FDOT2(u2h2(a3.y), u2h2(b0.y), acc[3][0]);
      acc[3][1] = FDOT2(u2h2(a3.y), u2h2(b1.y), acc[3][1]);
      acc[3][2] = FDOT2(u2h2(a3.y), u2h2(b2.y), acc[3][2]);
      acc[3][3] = FDOT2(u2h2(a3.y), u2h2(b3.y), acc[3][3]);
    }
  }

  const int col = n0 + tx * 4;
  float4 be = *reinterpret_cast<const float4*>(&beff[col]);

  if (n0 >= 256) {
    // z path: silu -> sz
#pragma unroll
    for (int i = 0; i < 4; ++i) {
      size_t row = m0 + ty * 4 + i;
      float v0 = acc[i][0] + be.x, v1 = acc[i][1] + be.y;
      float v2 = acc[i][2] + be.z, v3 = acc[i][3] + be.w;
      ushort4 o;
      o.x = f2bf(v0 / (1.f + __expf(-v0)));
      o.y = f2bf(v1 / (1.f + __expf(-v1)));
      o.z = f2bf(v2 / (1.f + __expf(-v2)));
      o.w = f2bf(v3 / (1.f + __expf(-v3)));
      *reinterpret_cast<ushort4*>(&sz[row * 256 + (col - 256)]) = o;
    }
    return;
  }

  // xi path: 3-row halo xz (rows m0-3..m0-1), masked at batch starts
  float haloval = 0.f;
  const int hc = tid & 63;
  if (tid < 192) {
    int hr = tid >> 6;
    long hrow = (long)m0 - 3 + hr;
    if (hrow < 0) hrow = 0;        // values masked by l-check below
    const uint4* hg = reinterpret_cast<const uint4*>(hbuf + (size_t)hrow * 128);
    const uint32_t* brow = &Bs[hc * S];
    float a0 = beff[n0 + hc], a1 = 0.f, a2 = 0.f, a3 = 0.f;
#pragma unroll
    for (int k = 0; k < 16; ++k) {
      uint4 hv = hg[k];
      a0 = FDOT2(u2h2(bfpair_to_h2(hv.x)), u2h2(brow[4 * k]),     a0);
      a1 = FDOT2(u2h2(bfpair_to_h2(hv.y)), u2h2(brow[4 * k + 1]), a1);
      a2 = FDOT2(u2h2(bfpair_to_h2(hv.z)), u2h2(brow[4 * k + 2]), a2);
      a3 = FDOT2(u2h2(bfpair_to_h2(hv.w)), u2h2(brow[4 * k + 3]), a3);
    }
    haloval = (a0 + a1) + (a2 + a3);
  }
  __syncthreads();   // As/Bs reads complete -> safe to overlay

  float* X = reinterpret_cast<float*>(smem);   // [67][68] fp32 xz tile
#pragma unroll
  for (int i = 0; i < 4; ++i) {
    int r = ty * 4 + i;
    float* q = &X[(r + 3) * 68 + tx * 4];
    q[0] = acc[i][0] + be.x; q[1] = acc[i][1] + be.y;
    q[2] = acc[i][2] + be.z; q[3] = acc[i][3] + be.w;
  }
  if (tid < 192) X[(tid >> 6) * 68 + hc] = haloval;
  __syncthreads();

  // conv (l-masked) + silu -> xs
  float cw0[4], cw1[4], cw2[4], cw3[4], cbv[4];
#pragma unroll
  for (int j = 0; j < 4; ++j) {
    int d = col + j;
    cw0[j] = cw[d * 4]; cw1[j] = cw[d * 4 + 1];
    cw2[j] = cw[d * 4 + 2]; cw3[j] = cw[d * 4 + 3];
    cbv[j] = cb[d];
  }
#pragma unroll
  for (int i = 0; i < 4; ++i) {
    int r = ty * 4 + i;
    size_t m = m0 + r;
    int l = (int)(m % LSEQ);
    const float* xr3 = &X[(r + 3) * 68 + tx * 4];  // current row
    ushort_t ov[4];
#pragma unroll
    for (int j = 0; j < 4; ++j) {
      float o0 = cbv[j];
      o0 += cw3[j] * xr3[j];
      if (l >= 1) o0 += cw2[j] * xr3[j - 68];
      if (l >= 2) o0 += cw1[j] * xr3[j - 136];
      if (l >= 3) o0 += cw0[j] * xr3[j - 204];
      ov[j] = f2bf(o0 / (1.f + __expf(-o0)));
    }
    ushort4 o; o.x = ov[0]; o.y = ov[1]; o.z = ov[2]; o.w = ov[3];
    *reinterpret_cast<ushort4*>(&xs[m * 256 + col]) = o;
  }
}

// ---------------------------------------------------------------------------
// K4: x_dbl = xs @ x_proj_w.T (N=40) via packed f16 dot2, b64 LDS reads.
__global__ __launch_bounds__(256) void k4_xdbl(
    const ushort_t* __restrict__ xs, const float* __restrict__ xpw,
    float* __restrict__ dtg, float* __restrict__ bc) {
  constexpr int XSTR = 134;
  __shared__ __align__(16) uint32_t xsh[64 * XSTR];
  __shared__ __align__(16) uint32_t wsh[40 * 128];
  const int tid = threadIdx.x;
  const size_t r0 = (size_t)blockIdx.x * 64;

  for (int i = tid; i < 64 * 128; i += 256) {
    int row = i >> 7, kk = i & 127;
    uint32_t v = *reinterpret_cast<const uint32_t*>(&xs[(r0 + row) * 256 + kk * 2]);
    xsh[row * XSTR + kk] = bfpair_to_h2(v);
  }
  for (int i = tid; i < 40 * 128; i += 256) {
    int c = i >> 7, kk = i & 127;
    half2_t h;
    h.x = (_Float16)xpw[c * 256 + kk * 2];
    h.y = (_Float16)xpw[c * 256 + kk * 2 + 1];
    wsh[i] = h22u(h);
  }
  __syncthreads();

  const int row = tid & 63;
  const int cg = tid >> 6;   // wave-uniform
  float acc[10] = {};
  for (int kk2 = 0; kk2 < 64; ++kk2) {
    uint2 xv = *reinterpret_cast<const uint2*>(&xsh[row * XSTR + kk2 * 2]);
    half2_t x0 = u2h2(xv.x), x1 = u2h2(xv.y);
#pragma unroll
    for (int i = 0; i < 10; ++i) {
      uint2 wv = *reinterpret_cast<const uint2*>(&wsh[(cg + 4 * i) * 128 + kk2 * 2]);
      acc[i] = FDOT2(x0, u2h2(wv.x), acc[i]);
      acc[i] = FDOT2(x1, u2h2(wv.y), acc[i]);
    }
  }
#pragma unroll
  for (int i = 0; i < 10; ++i) {
    int c = cg + 4 * i;
    if (c < 8) dtg[(r0 + row) * 8 + c] = acc[i];
    else bc[(r0 + row) * 32 + (c - 8)] = acc[i];
  }
}

// ---------------------------------------------------------------------------
// K5: selective scan. 8 threads per (b,d), 2 states each; reduction hoisted
//     out of the loop (z group-uniform); D-term via accD.
__global__ __launch_bounds__(256) void k5_scan(
    const float* __restrict__ dtg, const ushort_t* __restrict__ xs,
    const ushort_t* __restrict__ sz, const float* __restrict__ bc,
    const float* __restrict__ A_log, const float* __restrict__ Dv,
    const float* __restrict__ dtw, const float* __restrict__ dtb,
    float* __restrict__ ysum) {
  const int b  = blockIdx.x >> 3;
  const int d  = ((blockIdx.x & 7) << 5) + (threadIdx.x >> 3);  // 0..255
  const int sg = threadIdx.x & 7;                                // 2 states each

  const float Aa0 = -__expf(A_log[d * 16 + sg * 2]);
  const float Aa1 = -__expf(A_log[d * 16 + sg * 2 + 1]);
  float w8[8];
#pragma unroll
  for (int r = 0; r < 8; ++r) w8[r] = dtw[d * 8 + r];
  const float db = dtb[d];
  const float DD = Dv[d];

  float h0 = 0.f, h1 = 0.f;
  float acc = 0.f, accD = 0.f;
  const size_t base = (size_t)b * LSEQ;

  float4 dta_c = *reinterpret_cast<const float4*>(&dtg[base * 8]);
  float4 dtb_c = *reinterpret_cast<const float4*>(&dtg[base * 8 + 4]);
  float  xv_c  = bf2f(xs[base * 256 + d]);
  float  zv_c  = bf2f(sz[base * 256 + d]);
  float2 bv_c  = *reinterpret_cast<const float2*>(&bc[base * 32 + sg * 2]);
  float2 cv_c  = *reinterpret_cast<const float2*>(&bc[base * 32 + 16 + sg * 2]);

  for (int l = 0; l < LSEQ; ++l) {
    const size_t nrow = base + ((l + 1 < LSEQ) ? (l + 1) : l);
    float4 dta_n = *reinterpret_cast<const float4*>(&dtg[nrow * 8]);
    float4 dtb_n = *reinterpret_cast<const float4*>(&dtg[nrow * 8 + 4]);
    float  xv_n  = bf2f(xs[nrow * 256 + d]);
    float  zv_n  = bf2f(sz[nrow * 256 + d]);
    float2 bv_n  = *reinterpret_cast<const float2*>(&bc[nrow * 32 + sg * 2]);
    float2 cv_n  = *reinterpret_cast<const float2*>(&bc[nrow * 32 + 16 + sg * 2]);

    float a = db + dta_c.x * w8[0] + dta_c.y * w8[1] + dta_c.z * w8[2] + dta_c.w * w8[3]
                 + dtb_c.x * w8[4] + dtb_c.y * w8[5] + dtb_c.z * w8[6] + dtb_c.w * w8[7];
    float dl = (a > 20.f) ? a : __logf(1.f + __expf(a));
    float dx = dl * xv_c;
    h0 = __expf(dl * Aa0) * h0 + dx * bv_c.x;
    h1 = __expf(dl * Aa1) * h1 + dx * bv_c.y;
    acc += (h0 * cv_c.x + h1 * cv_c.y) * zv_c;
    accD += xv_c * zv_c;

    dta_c = dta_n; dtb_c = dtb_n;
    xv_c = xv_n; zv_c = zv_n; bv_c = bv_n; cv_c = cv_n;
  }
  if (sg == 0) acc += DD * accD;
  acc += __shfl_xor(acc, 1);
  acc += __shfl_xor(acc, 2);
  acc += __shfl_xor(acc, 4);
  if (sg == 0) ysum[b * 256 + d] = acc;
}

// ---------------------------------------------------------------------------
// K6: head. pooled = ysum@opw.T/L ; fc1+relu ; fc2.
__global__ __launch_bounds__(128) void k6_head(
    const float* __restrict__ ysum, const float* __restrict__ opw,
    const float* __restrict__ fc1w, const float* __restrict__ fc1b,
    const float* __restrict__ fc2w, const float* __restrict__ fc2b,
    float* __restrict__ out) {
  __shared__ float ys[256], pool[128], fcs[128];
  const int b = blockIdx.x, t = threadIdx.x;
  for (int i = t; i < 256; i += 128) ys[i] = ysum[b * 256 + i];
  __syncthreads();
  float a = 0.f;
  for (int e = 0; e < 256; ++e) a += opw[t * 256 + e] * ys[e];
  pool[t] = a * (1.0f / (float)LSEQ);
  __syncthreads();
  float a1 = fc1b[t];
  for (int d2 = 0; d2 < 128; ++d2) a1 += fc1w[t * 128 + d2] * pool[d2];
  fcs[t] = fmaxf(a1, 0.f);
  __syncthreads();
  if (t < NCL) {
    float o = fc2b[t];
    for (int f = 0; f < 128; ++f) o += fc2w[t * 128 + f] * fcs[f];
    out[b * NCL + t] = o;
  }
}

// ---------------------------------------------------------------------------
extern "C" void kernel_launch(void* const* d_in, const int* in_sizes, int n_in,
                              void* d_out, int out_size, void* d_ws, size_t ws_size,
                              hipStream_t stream) {
  const float* x     = (const float*)d_in[0];
  const float* W_ih  = (const float*)d_in[1];
  const float* W_hh  = (const float*)d_in[2];
  const float* b_ih  = (const float*)d_in[3];
  const float* b_hh  = (const float*)d_in[4];
  const float* Wp    = (const float*)d_in[5];
  const float* bp    = (const float*)d_in[6];
  const float* ipw   = (const float*)d_in[7];
  const float* cw    = (const float*)d_in[8];
  const float* cb    = (const float*)d_in[9];
  const float* xpw   = (const float*)d_in[10];
  const float* dtw   = (const float*)d_in[11];
  const float* dtb   = (const float*)d_in[12];
  const float* A_log = (const float*)d_in[13];
  const float* Dv    = (const float*)d_in[14];
  const float* opw   = (const float*)d_in[15];
  const float* fc1w  = (const float*)d_in[16];
  const float* fc1b  = (const float*)d_in[17];
  const float* fc2w  = (const float*)d_in[18];
  const float* fc2b  = (const float*)d_in[19];
  float* out = (float*)d_out;

  const size_t A_WEFF = 131072;                          // packed f16 pairs
  const size_t A_BEFF = 4096, A_YSUM = 131072;
  const size_t A_HBUF = (size_t)NB * LSEQ * HID * 2;     // 32.77 MB
  const size_t A_XS   = (size_t)NB * LSEQ * DINN * 2;    // 65.54 MB
  const size_t A_SZ   = A_XS;                            // 65.54 MB
  const size_t A_DT   = (size_t)NB * LSEQ * 8 * 4;       // 4.10 MB
  const size_t A_BC   = (size_t)NB * LSEQ * 32 * 4;      // 16.38 MB
  const size_t FIXED_WIDE = A_WEFF + A_BEFF + A_YSUM + A_HBUF + A_XS + A_SZ + A_DT + A_BC;
  // no xi buffer anymore: FIXED_WIDE = 184.6 MB

  if (FIXED_WIDE <= ws_size) {
    char* p = (char*)d_ws;
    uint32_t* Weffh = (uint32_t*)p; p += A_WEFF;
    float*    beff = (float*)p;    p += A_BEFF;
    float*    ysum = (float*)p;    p += A_YSUM;
    ushort_t* hbuf = (ushort_t*)p; p += A_HBUF;
    ushort_t* xsb  = (ushort_t*)p; p += A_XS;
    ushort_t* szb  = (ushort_t*)p; p += A_SZ;
    float*    dtg  = (float*)p;    p += A_DT;
    float*    bcb  = (float*)p;    p += A_BC;

    const int rows = NB * LSEQ;      // 128000
    hipLaunchKernelGGL(k0_weff, dim3(128), dim3(256), 0, stream, ipw, Wp, bp, Weffh, beff);
    hipLaunchKernelGGL(k1_lstm, dim3(NB), dim3(256), 0, stream, x, W_ih, W_hh, b_ih, b_hh, hbuf);
    hipLaunchKernelGGL(k2f, dim3(rows / 64, 8), dim3(256), 0, stream,
                       hbuf, Weffh, beff, cw, cb, xsb, szb);
    hipLaunchKernelGGL(k4_xdbl, dim3(rows / 64), dim3(256), 0, stream,
                       xsb, xpw, dtg, bcb);
    hipLaunchKernelGGL(k5_scan, dim3(NB * 8), dim3(256), 0, stream,
                       dtg, xsb, szb, bcb, A_log, Dv, dtw, dtb, ysum);
    hipLaunchKernelGGL(k6_head, dim3(NB), dim3(128), 0, stream,
                       ysum, opw, fc1w, fc1b, fc2w, fc2b, out);
    return;
  }

  // --- fallback: chunked over batches (same fused kernel; chunks start at
  //     batch boundaries so the conv l-masking stays correct) ---
  const size_t FIXED = A_WEFF + A_BEFF + A_YSUM + A_HBUF;
  const size_t PERB = (size_t)LSEQ * DINN * 2 * 2 + (size_t)LSEQ * 8 * 4 + (size_t)LSEQ * 32 * 4;
  int nb = 8;
  for (int c = 64; c >= 8; c >>= 1) {
    if (FIXED + (size_t)c * PERB <= ws_size) { nb = c; break; }
  }
  char* p = (char*)d_ws;
  uint32_t* Weffh = (uint32_t*)p; p += A_WEFF;
  float*    beff = (float*)p;    p += A_BEFF;
  float*    ysum = (float*)p;    p += A_YSUM;
  ushort_t* hbuf = (ushort_t*)p; p += A_HBUF;
  ushort_t* xsb  = (ushort_t*)p; p += (size_t)nb * LSEQ * DINN * 2;
  ushort_t* szb  = (ushort_t*)p; p += (size_t)nb * LSEQ * DINN * 2;
  float*    dtg  = (float*)p;    p += (size_t)nb * LSEQ * 8 * 4;
  float*    bcb  = (float*)p;

  hipLaunchKernelGGL(k0_weff, dim3(128), dim3(256), 0, stream, ipw, Wp, bp, Weffh, beff);
  hipLaunchKernelGGL(k1_lstm, dim3(NB), dim3(256), 0, stream, x, W_ih, W_hh, b_ih, b_hh, hbuf);
  for (int b0 = 0; b0 < NB; b0 += nb) {
    const int rows = nb * LSEQ;
    hipLaunchKernelGGL(k2f, dim3(rows / 64, 8), dim3(256), 0, stream,
                       hbuf + (size_t)b0 * LSEQ * HID, Weffh, beff, cw, cb, xsb, szb);
    hipLaunchKernelGGL(k4_xdbl, dim3(rows / 64), dim3(256), 0, stream, xsb, xpw, dtg, bcb);
    hipLaunchKernelGGL(k5_scan, dim3(nb * 8), dim3(256), 0, stream,
                       dtg, xsb, szb, bcb, A_log, Dv, dtw, dtb, ysum + (size_t)b0 * DINN);
  }
  hipLaunchKernelGGL(k6_head, dim3(NB), dim3(128), 0, stream,
                     ysum, opw, fc1w, fc1b, fc2w, fc2b, out);
}